// Round 2
// baseline (475.004 us; speedup 1.0000x reference)
//
#include <hip/hip_runtime.h>
#include <hip/hip_bf16.h>
#include <hip/hip_fp16.h>

// ============================================================================
// MinGRUCell forward, MI355X (gfx950).  Round 7 = round 6 + 8-phase GEMM.
//   zh = x @ W^T + b     (x,W rounded to bf16, MFMA GEMM)
//   h[t] = sigmoid(-z)*h[t-1] + sigmoid(z)*g(h_inter), h[-1]=hx  (linear scan)
//
// Round-7 change: GEMM rewritten from the m97 128-tile structure (measured
// plateau: 156us, MfmaUtil 39%, ~880 TF) to the 256x256 8-wave double-buffered
// schedule with COUNTED vmcnt (T3+T4), setprio around MFMA clusters (T5),
// XCD-aware block swizzle (T1), same proven XOR LDS swizzle (T2).
//   - LDS: A[2][256x64] + B[2][256x64] bf16 = 128 KiB, 1 block/CU, 512 thr.
//   - Tile T+2's global_load_lds issued at the boundary right after tile T
//     frees its buffer; waited with vmcnt(8) one boundary later (4 phases of
//     flight time).  No vmcnt(0) in the main loop.
//   - 4 phases per K-tile: phase p = A-frag rows {2p,2p+1} x 4 B-frags x K=64
//     (16 MFMA), two barriers per phase, setprio(1) around the cluster.
// Scan phases unchanged from round 6.
//
// Workspace: wb bf16 4MiB | zbuf fp16 64MiB | hbuf fp16 64MiB | seed 4MiB
// d_out scratch (until phase3 overwrites): xb [0,64MiB) | Aar,Bar [64,72MiB)
// ============================================================================

#define N_B   8
#define L_SEQ 4096
#define H_DIM 1024
#define K_DIM 1024
#define O_DIM 2048
#define M_TOT (N_B * L_SEQ)      // 32768 GEMM rows

#define BM 256
#define BN 256
#define BK 64
#define KTILES (K_DIM / BK)      // 16

#define NCHUNK 128
#define CLEN   (L_SEQ / NCHUNK)  // 32
#define NCH    (N_B * H_DIM)     // 8192 channels

typedef unsigned short ushort_t;
typedef unsigned short us8 __attribute__((ext_vector_type(8)));
typedef __bf16 v8bf __attribute__((ext_vector_type(8)));
typedef float f32x4 __attribute__((ext_vector_type(4)));

static __device__ __forceinline__ ushort_t f2bf(float f) {
    __hip_bfloat16 h = __float2bfloat16(f);   // RTN
    return *reinterpret_cast<ushort_t*>(&h);
}

// async global->LDS DMA, 16B per lane, LDS dest = wave-uniform base + lane*16
static __device__ __forceinline__ void dma16(const ushort_t* g, ushort_t* l) {
    __builtin_amdgcn_global_load_lds(
        (const __attribute__((address_space(1))) unsigned int*)g,
        (__attribute__((address_space(3))) unsigned int*)l,
        16, 0, 0);
}

// ---------------------------------------------------------------------------
// fp32 -> bf16 (8 elems/thread)
// ---------------------------------------------------------------------------
__global__ __launch_bounds__(256) void cvt_f32_bf16(
    const float* __restrict__ src, ushort_t* __restrict__ dst)
{
    const int i = blockIdx.x * 256 + threadIdx.x;
    const float4 f0 = ((const float4*)src)[2 * i];
    const float4 f1 = ((const float4*)src)[2 * i + 1];
    us8 o;
    o[0] = f2bf(f0.x); o[1] = f2bf(f0.y); o[2] = f2bf(f0.z); o[3] = f2bf(f0.w);
    o[4] = f2bf(f1.x); o[5] = f2bf(f1.y); o[6] = f2bf(f1.z); o[7] = f2bf(f1.w);
    ((us8*)dst)[i] = o;
}

// ---------------------------------------------------------------------------
// GEMM: C[m,o] = sum_k xb[m,k]*Wb[o,k] + b[o], 256x256 tile, 8 waves,
// 8-phase counted-vmcnt schedule.  mfma_f32_16x16x32_bf16.
// ---------------------------------------------------------------------------
__global__ __launch_bounds__(512, 2) void gemm_zh(
    const ushort_t* __restrict__ Xb,       // (M_TOT, K) bf16 bits
    const ushort_t* __restrict__ Wb,       // (O_DIM, K) bf16 bits
    const float* __restrict__ bias,        // (O_DIM) fp32
    __half* __restrict__ zbuf,             // (M_TOT, H_DIM) fp16
    __half* __restrict__ hbuf)             // (M_TOT, H_DIM) fp16
{
    __shared__ ushort_t As[2][BM * BK];    // 32 KiB each -> 128 KiB total
    __shared__ ushort_t Bs[2][BN * BK];

    const int tid  = threadIdx.x;
    const int wave = tid >> 6;             // 0..7
    const int lane = tid & 63;
    const int l15  = lane & 15;
    const int quad = lane >> 4;
    const int wr   = wave >> 2;            // 0..1  (M direction)
    const int wc   = wave & 3;             // 0..3  (N direction)

    // XCD-aware swizzle (1024 blocks, 1024%8==0 -> simple form is bijective):
    // each XCD gets a contiguous 16 m-tiles x 8 n-tiles slab.
    const int orig = blockIdx.x;
    const int wg   = (orig & 7) * (1024 / 8) + (orig >> 3);
    const int n0   = (wg & 7) * BN;        // 0..1792
    const int m0   = (wg >> 3) * BM;       // 0..32512

    // ---- staging addresses ------------------------------------------------
    // seg = l*512 + wave*64 + lane ; row(in half) = seg>>3 ; chunkpos = lane&7
    // source chunk = chunkpos ^ (row&7)  (pre-swizzled source, linear LDS)
    const int lrow3  = lane >> 3;                         // row&7
    const int colofs = ((lane & 7) ^ lrow3) * 8;
    const ushort_t* gA = Xb + (size_t)(m0 + wave * 8 + lrow3) * K_DIM + colofs;
    const ushort_t* gB = Wb + (size_t)(n0 + wave * 8 + lrow3) * K_DIM + colofs;
    const int ldst = wave * 512;           // wave-uniform LDS elem base

    // issue all 8 half-tile loads (2 per (h,l)) of K-tile kt into buffer b
#define STAGE(kt, b) do {                                                     \
        const size_t ko_ = (size_t)(kt) * BK;                                 \
        _Pragma("unroll")                                                     \
        for (int h_ = 0; h_ < 2; ++h_) {                                      \
            _Pragma("unroll")                                                 \
            for (int l_ = 0; l_ < 2; ++l_) {                                  \
                const size_t gofs_ = (size_t)(h_ * 128 + l_ * 64) * K_DIM;    \
                const int lofs_ = h_ * 8192 + l_ * 4096 + ldst;               \
                dma16(gA + gofs_ + ko_, &As[b][lofs_]);                       \
                dma16(gB + gofs_ + ko_, &Bs[b][lofs_]);                       \
            }                                                                 \
        }                                                                     \
    } while (0)

    // ---- fragment read offsets (XOR swizzle matches staging) --------------
    // row&7 == l15&7 for both A and B frag rows
    int xt[2];
#pragma unroll
    for (int s = 0; s < 2; ++s) xt[s] = (((s * 4 + quad) ^ (l15 & 7)) * 8);
    const int arow0 = (wr * 128 + l15) * BK;   // + i*16*BK
    const int brow0 = (wc * 64 + l15) * BK;    // + j*16*BK

    const f32x4 fzero = {0.f, 0.f, 0.f, 0.f};
    f32x4 acc[8][4];
#pragma unroll
    for (int i = 0; i < 8; ++i)
#pragma unroll
        for (int j = 0; j < 4; ++j)
            acc[i][j] = fzero;

    v8bf bfr[4][2];

    // ---- prologue: stage K-tiles 0 and 1, wait tile 0 ---------------------
    STAGE(0, 0);
    STAGE(1, 1);
    asm volatile("s_waitcnt vmcnt(8)" ::: "memory");   // tile0 landed
    __builtin_amdgcn_s_barrier();
    asm volatile("" ::: "memory");

    for (int kt = 0; kt < KTILES; ++kt) {
        const int b = kt & 1;

#pragma unroll
        for (int p = 0; p < 4; ++p) {
            if (p == 0) {
#pragma unroll
                for (int j = 0; j < 4; ++j)
#pragma unroll
                    for (int s = 0; s < 2; ++s)
                        bfr[j][s] = *(const v8bf*)&Bs[b][brow0 + j * 16 * BK + xt[s]];
            }
            v8bf af[2][2];
#pragma unroll
            for (int u = 0; u < 2; ++u)
#pragma unroll
                for (int s = 0; s < 2; ++s)
                    af[u][s] = *(const v8bf*)&As[b][arow0 + (2 * p + u) * 16 * BK + xt[s]];

            // pre-MFMA barrier: waves enter the MFMA cluster together
            asm volatile("" ::: "memory");
            __builtin_amdgcn_s_barrier();

            __builtin_amdgcn_s_setprio(1);
#pragma unroll
            for (int s = 0; s < 2; ++s)
#pragma unroll
                for (int u = 0; u < 2; ++u)
#pragma unroll
                    for (int j = 0; j < 4; ++j)
                        acc[2 * p + u][j] = __builtin_amdgcn_mfma_f32_16x16x32_bf16(
                            af[u][s], bfr[j][s], acc[2 * p + u][j], 0, 0, 0);
            __builtin_amdgcn_s_setprio(0);

            if (p < 3) {
                asm volatile("" ::: "memory");
                __builtin_amdgcn_s_barrier();
                asm volatile("" ::: "memory");
            }
        }

        // ---- tile boundary ------------------------------------------------
        if (kt < KTILES - 1) {
            // all waves done reading buffer b -> safe to restage it
            asm volatile("" ::: "memory");
            __builtin_amdgcn_s_barrier();
            asm volatile("" ::: "memory");
            if (kt + 2 < KTILES) {
                STAGE(kt + 2, b);                          // into just-freed buf
                asm volatile("s_waitcnt vmcnt(8)" ::: "memory");  // tile kt+1 in
            } else {
                asm volatile("s_waitcnt vmcnt(0)" ::: "memory");  // last tile in
            }
            __builtin_amdgcn_s_barrier();
            asm volatile("" ::: "memory");
        }
    }
#undef STAGE

    // ---- epilogue ---------------------------------------------------------
    float bv[4];
#pragma unroll
    for (int j = 0; j < 4; ++j)
        bv[j] = bias[n0 + wc * 64 + j * 16 + l15];

    __half* outb = (n0 < H_DIM) ? zbuf : hbuf;      // block-uniform
    const int colbase = (n0 & (H_DIM - 1)) + wc * 64 + l15;

#pragma unroll
    for (int i = 0; i < 8; ++i) {
#pragma unroll
        for (int r = 0; r < 4; ++r) {
            const size_t row = (size_t)(m0 + wr * 128 + i * 16 + quad * 4 + r);
            __half* p = outb + row * H_DIM + colbase;
#pragma unroll
            for (int j = 0; j < 4; ++j)
                p[j * 16] = __float2half(acc[i][j][r] + bv[j]);
        }
    }
}

// ---------------------------------------------------------------------------
// Gating math (identical in phases 1 and 3).
// a = sigmoid(-z), v = sigmoid(z)*g(hi);  g(x) = x+0.5 (x>=0) else sigmoid(x)
// ---------------------------------------------------------------------------
__device__ __forceinline__ void gate_av(float z, float hi, float& a, float& v)
{
    const float e  = __expf(-z);
    const float sz = 1.0f / (1.0f + e);        // sigmoid(z)
    a = e * sz;                                // sigmoid(-z)
    const float g = (hi >= 0.0f) ? (hi + 0.5f)
                                 : (1.0f / (1.0f + __expf(-hi)));
    v = sz * g;
}

// Phase 1: per-(4-channel group, chunk) affine summary  h_out = A*h_in + B.
__global__ __launch_bounds__(256) void scan_phase1(
    const __half* __restrict__ zbuf, const __half* __restrict__ hbuf,
    float* __restrict__ Aar, float* __restrict__ Bar)
{
    const int idx = blockIdx.x * 256 + threadIdx.x;   // 0..262143
    const int h4  = (idx & 255) << 2;                 // 0..1020
    const int n   = (idx >> 8) & 7;
    const int c   = idx >> 11;                        // 0..127
    const size_t base = ((size_t)(n * L_SEQ + c * CLEN)) * H_DIM + h4;
    const float2* zp = (const float2*)(zbuf + base);  // float2 == 4 halves
    const float2* hp = (const float2*)(hbuf + base);

    float A[4], B[4];
#pragma unroll
    for (int j = 0; j < 4; ++j) { A[j] = 1.f; B[j] = 0.f; }

#pragma unroll 8
    for (int s = 0; s < CLEN; ++s) {
        float2 zr = zp[(size_t)s * (H_DIM / 4)];
        float2 hr = hp[(size_t)s * (H_DIM / 4)];
        const __half2* z2 = (const __half2*)&zr;
        const __half2* i2 = (const __half2*)&hr;
#pragma unroll
        for (int j = 0; j < 2; ++j) {
            const float2 z  = __half22float2(z2[j]);
            const float2 hi = __half22float2(i2[j]);
            float a, v;
            gate_av(z.x, hi.x, a, v);
            B[2*j]   = fmaf(a, B[2*j],   v);  A[2*j]   *= a;
            gate_av(z.y, hi.y, a, v);
            B[2*j+1] = fmaf(a, B[2*j+1], v);  A[2*j+1] *= a;
        }
    }
    const size_t o = (size_t)c * NCH + n * H_DIM + h4;
    *(f32x4*)(Aar + o) = *(const f32x4*)&A[0];
    *(f32x4*)(Bar + o) = *(const f32x4*)&B[0];
}

// Phase 2: compose NCHUNK chunk summaries per channel, seeded with hx (fp32).
__global__ __launch_bounds__(256) void scan_phase2(
    const float* __restrict__ Aar, const float* __restrict__ Bar,
    const float* __restrict__ hx, float* __restrict__ seed)
{
    const int ch = blockIdx.x * 256 + threadIdx.x;    // 0..8191
    float carry = hx[ch];
#pragma unroll 8
    for (int c = 0; c < NCHUNK; ++c) {
        seed[c * NCH + ch] = carry;
        carry = fmaf(Aar[c * NCH + ch], carry, Bar[c * NCH + ch]);
    }
}

// Phase 3: replay each chunk from its seed; nontemporal fp32 stores.
__global__ __launch_bounds__(256) void scan_phase3(
    const __half* __restrict__ zbuf, const __half* __restrict__ hbuf,
    const float* __restrict__ seed, float* __restrict__ out)
{
    const int idx = blockIdx.x * 256 + threadIdx.x;
    const int h4  = (idx & 255) << 2;
    const int n   = (idx >> 8) & 7;
    const int c   = idx >> 11;
    const size_t base = ((size_t)(n * L_SEQ + c * CLEN)) * H_DIM + h4;
    const float2* zp = (const float2*)(zbuf + base);
    const float2* hp = (const float2*)(hbuf + base);
    float* op = out + base;

    const size_t so = (size_t)c * NCH + n * H_DIM + h4;
    float h0[4];
    *(f32x4*)h0 = *(const f32x4*)(seed + so);

#pragma unroll 8
    for (int s = 0; s < CLEN; ++s) {
        float2 zr = zp[(size_t)s * (H_DIM / 4)];
        float2 hr = hp[(size_t)s * (H_DIM / 4)];
        const __half2* z2 = (const __half2*)&zr;
        const __half2* i2 = (const __half2*)&hr;
#pragma unroll
        for (int j = 0; j < 2; ++j) {
            const float2 za = __half22float2(z2[j]);
            const float2 ia = __half22float2(i2[j]);
            float a, v;
            gate_av(za.x, ia.x, a, v);  h0[2*j]   = fmaf(a, h0[2*j],   v);
            gate_av(za.y, ia.y, a, v);  h0[2*j+1] = fmaf(a, h0[2*j+1], v);
        }
        f32x4 hv = *(const f32x4*)h0;
        __builtin_nontemporal_store(hv, (f32x4*)(op + (size_t)s * H_DIM));
    }
}

// ---------------------------------------------------------------------------
extern "C" void kernel_launch(void* const* d_in, const int* in_sizes, int n_in,
                              void* d_out, int out_size, void* d_ws, size_t ws_size,
                              hipStream_t stream)
{
    const float* X    = (const float*)d_in[0];   // x  (8,4096,1024) fp32
    const float* Wm   = (const float*)d_in[1];   // W  (2048,1024)   fp32
    const float* bias = (const float*)d_in[2];   // b  (2048)        fp32
    const float* hx   = (const float*)d_in[3];   // hx (8,1024)      fp32
    float* out = (float*)d_out;                  // (8,4096,1024)    fp32

    char* ws = (char*)d_ws;
    ushort_t* wb = (ushort_t*)ws;                                  //  4 MiB
    __half* zbuf = (__half*)(ws + (size_t)O_DIM * K_DIM * 2);      // 64 MiB
    __half* hbuf = zbuf + (size_t)M_TOT * H_DIM;                   // 64 MiB
    float*  seed = (float*)(hbuf + (size_t)M_TOT * H_DIM);         //  4 MiB

    // d_out (128 MiB) doubles as scratch until phase3 overwrites it:
    //   bytes [0, 64Mi):   x_bf16  (M_TOT*K_DIM*2 B = exactly half)
    //   bytes [64Mi,72Mi): Aar, Bar (NCHUNK*NCH fp32 each)
    ushort_t* xb = (ushort_t*)d_out;
    float* Aar = out + (size_t)M_TOT * H_DIM / 2;      // true halfway point
    float* Bar = Aar + (size_t)NCHUNK * NCH;

    cvt_f32_bf16<<<O_DIM * K_DIM / 8 / 256, 256, 0, stream>>>(Wm, wb);
    cvt_f32_bf16<<<M_TOT * K_DIM / 8 / 256, 256, 0, stream>>>(X, xb);

    const int ggrid = (O_DIM / BN) * (M_TOT / BM);     // 8 * 128 = 1024
    gemm_zh<<<ggrid, 512, 0, stream>>>(xb, wb, bias, zbuf, hbuf);

    const int p13_blocks = (NCH / 4) * NCHUNK / 256;   // 1024
    scan_phase1<<<p13_blocks, 256, 0, stream>>>(zbuf, hbuf, Aar, Bar);
    scan_phase2<<<NCH / 256, 256, 0, stream>>>(Aar, Bar, hx, seed);
    scan_phase3<<<p13_blocks, 256, 0, stream>>>(zbuf, hbuf, seed, out);
}

// Round 3
// 443.474 us; speedup vs baseline: 1.0711x; 1.0711x over previous
//
#include <hip/hip_runtime.h>
#include <hip/hip_bf16.h>
#include <hip/hip_fp16.h>

// ============================================================================
// MinGRUCell forward, MI355X (gfx950).  Round 8 = revert GEMM to proven m97
// structure (156us) + FUSE phase1 into the GEMM epilogue.
//
//   zh = x @ W'^T + b'   (W rows permuted: 16-col z-block / h-block alternate,
//                         so each tile holds z AND h_inter of the same channels)
//   epilogue: a = sigmoid(-z), v = sigmoid(z)*g(h_inter)  ->  avbuf (__half2)
//             + per-chunk affine summaries (A,B) via in-register quad
//             butterfly (__shfl_xor 16/32) -> Aar/Bar  [phase1 ELIMINATED]
//   phase2: compose 128 chunk summaries per channel, seeded with hx
//   phase3: pure replay h = fma(a,h,v), 16B av loads, nontemporal f32 stores
//
// Round-7 8-phase GEMM regressed (168us, MfmaUtil 34%): burst staging +
// extra barriers + compiler LDS-DMA drains defeated the counted-vmcnt
// pipeline.  Reverted.  (Its one win, FETCH 274->98MB via T1+256^2, is moot
// while the GEMM is schedule-bound, not BW-bound.)
//
// Workspace: wb bf16 4MiB | avbuf half2 128MiB | seed 4MiB | biasp 8KB
// d_out scratch (until phase3 overwrites): xb [0,64Mi) | Aar,Bar [64,72Mi)
// ============================================================================

#define N_B   8
#define L_SEQ 4096
#define H_DIM 1024
#define K_DIM 1024
#define O_DIM 2048
#define M_TOT (N_B * L_SEQ)      // 32768 GEMM rows

#define BM 128
#define BN 128
#define BK 64

#define NCHUNK 128
#define CLEN   (L_SEQ / NCHUNK)  // 32
#define NCH    (N_B * H_DIM)     // 8192 channels

typedef unsigned short ushort_t;
typedef unsigned short us8 __attribute__((ext_vector_type(8)));
typedef __bf16 v8bf __attribute__((ext_vector_type(8)));
typedef float f32x4 __attribute__((ext_vector_type(4)));

static __device__ __forceinline__ ushort_t f2bf(float f) {
    __hip_bfloat16 h = __float2bfloat16(f);   // RTN
    return *reinterpret_cast<ushort_t*>(&h);
}

// async global->LDS DMA, 16B per lane, LDS dest = wave-uniform base + lane*16
static __device__ __forceinline__ void dma16(const ushort_t* g, ushort_t* l) {
    __builtin_amdgcn_global_load_lds(
        (const __attribute__((address_space(1))) unsigned int*)g,
        (__attribute__((address_space(3))) unsigned int*)l,
        16, 0, 0);
}

// ---------------------------------------------------------------------------
// fp32 -> bf16 (8 elems/thread), straight copy (used for X)
// ---------------------------------------------------------------------------
__global__ __launch_bounds__(256) void cvt_f32_bf16(
    const float* __restrict__ src, ushort_t* __restrict__ dst)
{
    const int i = blockIdx.x * 256 + threadIdx.x;
    const float4 f0 = ((const float4*)src)[2 * i];
    const float4 f1 = ((const float4*)src)[2 * i + 1];
    us8 o;
    o[0] = f2bf(f0.x); o[1] = f2bf(f0.y); o[2] = f2bf(f0.z); o[3] = f2bf(f0.w);
    o[4] = f2bf(f1.x); o[5] = f2bf(f1.y); o[6] = f2bf(f1.z); o[7] = f2bf(f1.w);
    ((us8*)dst)[i] = o;
}

// ---------------------------------------------------------------------------
// fp32 -> bf16 W with row permutation: dest row o' in 16-row blocks B=o'>>4,
// t=o'&15: B even -> z row (B>>1)*16+t ; B odd -> h row 1024+(B>>1)*16+t.
// So channel c has z at col (c>>4)*32+(c&15), h at +16.
// ---------------------------------------------------------------------------
__global__ __launch_bounds__(256) void cvt_w_perm(
    const float* __restrict__ src, ushort_t* __restrict__ dst)
{
    const int i  = blockIdx.x * 256 + threadIdx.x;  // 262144 threads
    const int op = i >> 7;                          // dest row 0..2047
    const int k  = (i & 127) * 8;
    const int B  = op >> 4, t = op & 15;
    const int orig = (B & 1) * 1024 + (B >> 1) * 16 + t;
    const float4* s = (const float4*)(src + (size_t)orig * K_DIM + k);
    const float4 f0 = s[0], f1 = s[1];
    us8 o;
    o[0] = f2bf(f0.x); o[1] = f2bf(f0.y); o[2] = f2bf(f0.z); o[3] = f2bf(f0.w);
    o[4] = f2bf(f1.x); o[5] = f2bf(f1.y); o[6] = f2bf(f1.z); o[7] = f2bf(f1.w);
    *(us8*)(dst + (size_t)op * K_DIM + k) = o;
}

// bias with the same permutation (fp32)
__global__ __launch_bounds__(256) void bias_perm(
    const float* __restrict__ b, float* __restrict__ bp)
{
    const int i = blockIdx.x * 256 + threadIdx.x;   // 0..2047
    const int B = i >> 4, t = i & 15;
    bp[i] = b[(B & 1) * 1024 + (B >> 1) * 16 + t];
}

// ---------------------------------------------------------------------------
// Gating math.  a = sigmoid(-z), v = sigmoid(z)*g(hi)
// g(x) = x+0.5 (x>=0) else sigmoid(x)
// ---------------------------------------------------------------------------
__device__ __forceinline__ void gate_av(float z, float hi, float& a, float& v)
{
    const float e  = __expf(-z);
    const float sz = 1.0f / (1.0f + e);        // sigmoid(z)
    a = e * sz;                                // sigmoid(-z)
    const float g = (hi >= 0.0f) ? (hi + 0.5f)
                                 : (1.0f / (1.0f + __expf(-hi)));
    v = sz * g;
}

// ---------------------------------------------------------------------------
// GEMM (m97 structure, proven 156us) + fused gate/phase1 epilogue.
// C[m,o'] = sum_k xb[m,k]*Wb'[o',k] + b'[o']; 128x128 tile, 4 waves,
// mfma_f32_16x16x32_bf16, global_load_lds staging, XOR source swizzle.
// ---------------------------------------------------------------------------
__global__ __launch_bounds__(256) void gemm_zh(
    const ushort_t* __restrict__ Xb,       // (M_TOT, K) bf16 bits
    const ushort_t* __restrict__ Wb,       // (O_DIM, K) bf16 bits, PERMUTED
    const float* __restrict__ biasp,       // (O_DIM) fp32, PERMUTED
    __half2* __restrict__ avbuf,           // (M_TOT, H_DIM) half2 {a,v}
    float* __restrict__ Aar,               // (NCHUNK, NCH) chunk A
    float* __restrict__ Bar)               // (NCHUNK, NCH) chunk B
{
    __shared__ ushort_t As[BM * BK];
    __shared__ ushort_t Bs[BN * BK];

    const int tid    = threadIdx.x;
    const int wave   = tid >> 6;
    const int lane   = tid & 63;
    const int lane15 = lane & 15;
    const int quad   = lane >> 4;

    const int n0 = blockIdx.x * BN;        // O-tile fast -> A-tile L2 reuse
    const int m0 = blockIdx.y * BM;

    const int lrow = lane >> 3;            // 0..7
    const int jj   = (lane & 7) ^ lrow;    // global chunk (xor swizzle)
    const ushort_t* gA = Xb + (size_t)(m0 + wave * 8 + lrow) * K_DIM + jj * 8;
    const ushort_t* gB = Wb + (size_t)(n0 + wave * 8 + lrow) * K_DIM + jj * 8;
    ushort_t* lA = &As[(wave * 8) * BK];
    ushort_t* lB = &Bs[(wave * 8) * BK];

    const int wm = (wave >> 1) * 64;
    const int wn = (wave & 1) * 64;

    int offA[2][4], offB[2][4];
#pragma unroll
    for (int s = 0; s < 2; ++s) {
#pragma unroll
        for (int t = 0; t < 4; ++t) {
            const int rowA = wm + t * 16 + lane15;
            offA[s][t] = rowA * BK + (((s * 4 + quad) ^ (rowA & 7)) * 8);
            const int rowB = wn + t * 16 + lane15;
            offB[s][t] = rowB * BK + (((s * 4 + quad) ^ (rowB & 7)) * 8);
        }
    }

    const f32x4 fzero = {0.f, 0.f, 0.f, 0.f};
    f32x4 acc[4][4];
#pragma unroll
    for (int i = 0; i < 4; ++i)
#pragma unroll
        for (int j = 0; j < 4; ++j)
            acc[i][j] = fzero;

    for (int kt = 0; kt < K_DIM / BK; ++kt) {
        __syncthreads();
#pragma unroll
        for (int r = 0; r < 4; ++r) {
            dma16(gA + (size_t)r * 32 * K_DIM + kt * BK, lA + r * 32 * BK);
            dma16(gB + (size_t)r * 32 * K_DIM + kt * BK, lB + r * 32 * BK);
        }
        __syncthreads();

#pragma unroll
        for (int s = 0; s < 2; ++s) {
            v8bf af[4], bfr[4];
#pragma unroll
            for (int t = 0; t < 4; ++t) af[t]  = *(const v8bf*)(&As[offA[s][t]]);
#pragma unroll
            for (int t = 0; t < 4; ++t) bfr[t] = *(const v8bf*)(&Bs[offB[s][t]]);
#pragma unroll
            for (int i = 0; i < 4; ++i)
#pragma unroll
                for (int j = 0; j < 4; ++j)
                    acc[i][j] = __builtin_amdgcn_mfma_f32_16x16x32_bf16(
                        af[i], bfr[j], acc[i][j], 0, 0, 0);
        }
    }

    // ---- fused epilogue ---------------------------------------------------
    // columns: j even = z-block, j odd = h-block of same 16 channels.
    // channel for pair jp: ch = (n0+wn)/2 + jp*16 + lane15
    float bv[4];
#pragma unroll
    for (int j = 0; j < 4; ++j)
        bv[j] = biasp[n0 + wn + j * 16 + lane15];

    const int chbase = ((n0 + wn) >> 1) + lane15;   // + jp*16

    float Ai[4][2], Bi[4][2];   // per-(i-frag, jp) 16-row affine summaries

#pragma unroll
    for (int i = 0; i < 4; ++i) {
        float A[2] = {1.f, 1.f};
        float Bc[2] = {0.f, 0.f};
#pragma unroll
        for (int r = 0; r < 4; ++r) {
            const size_t row = (size_t)(m0 + wm + i * 16 + quad * 4 + r);
            __half2* prow = avbuf + row * H_DIM + chbase;
#pragma unroll
            for (int jp = 0; jp < 2; ++jp) {
                const float z  = acc[i][2 * jp][r]     + bv[2 * jp];
                const float hh = acc[i][2 * jp + 1][r] + bv[2 * jp + 1];
                float a, v;
                gate_av(z, hh, a, v);
                const __half2 h2 = __floats2half2_rn(a, v);
                prow[jp * 16] = h2;
                // compose with the SAME fp16-rounded values phase3 will use
                const float2 f = __half22float2(h2);
                Bc[jp] = fmaf(f.x, Bc[jp], f.y);
                A[jp] *= f.x;
            }
        }
        // ordered compose across quads (rows i*16 + quad*4 + r are
        // (quad,r)-lexicographic): butterfly on lane bits 16 and 32.
#pragma unroll
        for (int jp = 0; jp < 2; ++jp) {
#pragma unroll
            for (int d = 16; d < 64; d <<= 1) {
                const float Ay = __shfl_xor(A[jp],  d);
                const float By = __shfl_xor(Bc[jp], d);
                // bit set -> I am the LATER block: (A,B) o (Ay,By)
                Bc[jp] = (lane & d) ? fmaf(A[jp], By, Bc[jp])
                                    : fmaf(Ay, Bc[jp], By);
                A[jp] *= Ay;
            }
            Ai[i][jp] = A[jp];
            Bi[i][jp] = Bc[jp];
        }
    }

    // chunk (32 rows) = frags {2cc, 2cc+1}; all quads hold identical values,
    // quad 0 writes.
    if (lane < 16) {
#pragma unroll
        for (int cc = 0; cc < 2; ++cc) {
            const int grow = m0 + wm + cc * 32;
            const int n    = grow >> 12;            // batch
            const int cch  = (grow & (L_SEQ - 1)) >> 5;   // chunk id
            const size_t o = (size_t)cch * NCH + (size_t)n * H_DIM + chbase;
#pragma unroll
            for (int jp = 0; jp < 2; ++jp) {
                const float A0 = Ai[2 * cc][jp],     B0 = Bi[2 * cc][jp];
                const float A1 = Ai[2 * cc + 1][jp], B1 = Bi[2 * cc + 1][jp];
                Aar[o + jp * 16] = A1 * A0;
                Bar[o + jp * 16] = fmaf(A1, B0, B1);
            }
        }
    }
}

// ---------------------------------------------------------------------------
// Phase 2: compose NCHUNK chunk summaries per channel, seeded with hx (fp32).
// ---------------------------------------------------------------------------
__global__ __launch_bounds__(256) void scan_phase2(
    const float* __restrict__ Aar, const float* __restrict__ Bar,
    const float* __restrict__ hx, float* __restrict__ seed)
{
    const int ch = blockIdx.x * 256 + threadIdx.x;    // 0..8191
    float carry = hx[ch];
#pragma unroll 8
    for (int c = 0; c < NCHUNK; ++c) {
        seed[c * NCH + ch] = carry;
        carry = fmaf(Aar[c * NCH + ch], carry, Bar[c * NCH + ch]);
    }
}

// ---------------------------------------------------------------------------
// Phase 3: pure replay from seed: h = fma(a, h, v).  4 ch/thread, 16B av
// loads, nontemporal fp32 stores.
// ---------------------------------------------------------------------------
__global__ __launch_bounds__(256) void scan_phase3(
    const __half2* __restrict__ avbuf,
    const float* __restrict__ seed, float* __restrict__ out)
{
    const int idx = blockIdx.x * 256 + threadIdx.x;
    const int h4  = (idx & 255) << 2;
    const int n   = (idx >> 8) & 7;
    const int c   = idx >> 11;
    const size_t base = ((size_t)(n * L_SEQ + c * CLEN)) * H_DIM + h4;
    const float4* avp = (const float4*)(avbuf + base);  // 4 half2 = 16B
    float* op = out + base;

    const size_t so = (size_t)c * NCH + n * H_DIM + h4;
    float h0[4];
    *(f32x4*)h0 = *(const f32x4*)(seed + so);

#pragma unroll 8
    for (int s = 0; s < CLEN; ++s) {
        float4 avr = avp[(size_t)s * (H_DIM / 4)];
        const __half2* a2 = (const __half2*)&avr;
#pragma unroll
        for (int j = 0; j < 4; ++j) {
            const float2 av = __half22float2(a2[j]);
            h0[j] = fmaf(av.x, h0[j], av.y);
        }
        f32x4 hv = *(const f32x4*)h0;
        __builtin_nontemporal_store(hv, (f32x4*)(op + (size_t)s * H_DIM));
    }
}

// ---------------------------------------------------------------------------
extern "C" void kernel_launch(void* const* d_in, const int* in_sizes, int n_in,
                              void* d_out, int out_size, void* d_ws, size_t ws_size,
                              hipStream_t stream)
{
    const float* X    = (const float*)d_in[0];   // x  (8,4096,1024) fp32
    const float* Wm   = (const float*)d_in[1];   // W  (2048,1024)   fp32
    const float* bias = (const float*)d_in[2];   // b  (2048)        fp32
    const float* hx   = (const float*)d_in[3];   // hx (8,1024)      fp32
    float* out = (float*)d_out;                  // (8,4096,1024)    fp32

    char* ws = (char*)d_ws;
    ushort_t* wb   = (ushort_t*)ws;                                 //   4 MiB
    __half2*  avbuf = (__half2*)(ws + (size_t)O_DIM * K_DIM * 2);   // 128 MiB
    float*    seed = (float*)((char*)avbuf + (size_t)M_TOT * H_DIM * 4); // 4 MiB
    float*    biasp = seed + (size_t)NCHUNK * NCH;                  //   8 KiB

    // d_out (128 MiB) doubles as scratch until phase3 overwrites it:
    //   bytes [0, 64Mi):   x_bf16  (M_TOT*K_DIM*2 B = exactly half)
    //   bytes [64Mi,72Mi): Aar, Bar (NCHUNK*NCH fp32 each)
    ushort_t* xb = (ushort_t*)d_out;
    float* Aar = out + (size_t)M_TOT * H_DIM / 2;      // true halfway point
    float* Bar = Aar + (size_t)NCHUNK * NCH;

    cvt_w_perm<<<O_DIM * K_DIM / 8 / 256, 256, 0, stream>>>(Wm, wb);
    bias_perm<<<O_DIM / 256, 256, 0, stream>>>(bias, biasp);
    cvt_f32_bf16<<<M_TOT * K_DIM / 8 / 256, 256, 0, stream>>>(X, xb);

    dim3 ggrid(O_DIM / BN, M_TOT / BM);          // (16, 256): O fast for reuse
    gemm_zh<<<ggrid, 256, 0, stream>>>(xb, wb, biasp, avbuf, Aar, Bar);

    scan_phase2<<<NCH / 256, 256, 0, stream>>>(Aar, Bar, hx, seed);

    const int p3_blocks = (NCH / 4) * NCHUNK / 256;    // 1024
    scan_phase3<<<p3_blocks, 256, 0, stream>>>(avbuf, seed, out);
}